// Round 2
// baseline (189.227 us; speedup 1.0000x reference)
//
#include <hip/hip_runtime.h>
#include <hip/hip_bf16.h>

// Problem constants (fixed by reference): B=8, C=128, N=M=4096, OUT=128
#define BATCH 8
#define CDIM 128
#define NDIM 4096

typedef __bf16 bf16x8 __attribute__((ext_vector_type(8)));
typedef float f32x4 __attribute__((ext_vector_type(4)));
typedef float f32x16 __attribute__((ext_vector_type(16)));
typedef unsigned u32x4 __attribute__((ext_vector_type(4)));

// workspace layout (bytes)
#define QT_OFF 0u                      // bf16 [8][4096][128]  normalized target_g (x log2e), transposed
#define KT_OFF 8388608u                // bf16 [8][4096][128]  normalized input, transposed
#define VB_OFF 16777216u               // bf16 [8][128][4096]  raw input
#define WT_OFF 25165824u               // bf16 [128][128]      weight transposed: wT[o][c]
#define SC_OFF (WT_OFF + 32768u)       // f32 [128] scale = gamma*rsqrt(var+eps)
#define BI_OFF (SC_OFF + 512u)         // f32 [128] bias  = beta - mean*scale

__device__ __forceinline__ f32x4 mfma16(bf16x8 a, bf16x8 b, f32x4 c) {
    return __builtin_amdgcn_mfma_f32_16x16x32_bf16(a, b, c, 0, 0, 0);
}
__device__ __forceinline__ f32x16 mfma32(bf16x8 a, bf16x8 b, f32x16 c) {
    return __builtin_amdgcn_mfma_f32_32x32x16_bf16(a, b, c, 0, 0, 0);
}

__device__ __forceinline__ unsigned pack2bf(float a, float b) {
    unsigned short ul = __builtin_bit_cast(unsigned short, (__bf16)a);
    unsigned short uh = __builtin_bit_cast(unsigned short, (__bf16)b);
    return (unsigned)ul | ((unsigned)uh << 16);
}

__device__ __forceinline__ void glds16(const void* g, void* l) {
    __builtin_amdgcn_global_load_lds((__attribute__((address_space(1))) void*)(void*)g,
                                     (__attribute__((address_space(3))) void*)l, 16, 0, 0);
}

// v_permlane32_swap_b32: a'[0:31]=a[0:31], a'[32:63]=b[0:31] ; b'[0:31]=a[32:63], b'[32:63]=b[32:63]
__device__ __forceinline__ void pls32(unsigned& a, unsigned& b) {
    asm("v_permlane32_swap_b32 %0, %1" : "+v"(a), "+v"(b));
}

__device__ __forceinline__ float vexp2(float x) {
    float r;
    asm("v_exp_f32 %0, %1" : "=v"(r) : "v"(x));
    return r;
}

// ---------------------------------------------------------------------------
// Pass 1: per-column L2 normalize over C + transpose to [n][c] bf16.
// z==0: input -> Kt + Vb ; z==1: target_g -> Qt scaled by log2(e)
// (so S' = S*log2e and P = 2^S' = e^S; the old exp(S-1) differs by a
// uniform factor e which cancels in the softmax normalization).
// ---------------------------------------------------------------------------
__global__ __launch_bounds__(256) void prep_nt(const float* __restrict__ input,
                                               const float* __restrict__ tg,
                                               const float* __restrict__ wgt,
                                               const float* __restrict__ gamma,
                                               const float* __restrict__ beta,
                                               const float* __restrict__ mean,
                                               const float* __restrict__ var,
                                               void* __restrict__ ws) {
    __shared__ float Tt[64][129];     // [n-local][c], pitch 129
    __shared__ float psum[4][64];
    __shared__ float rn[64];
    const int n0 = blockIdx.x * 64;
    const int b  = blockIdx.y;
    const int tid = threadIdx.x;
    const float* src = (blockIdx.z == 0 ? input : tg) + (size_t)b * CDIM * NDIM;
    const float zscale = (blockIdx.z == 0) ? 1.0f : 1.4426950408889634f;

    #pragma unroll
    for (int i = 0; i < 8; ++i) {
        int f = tid + i * 256;
        int c = f >> 4, j4 = f & 15;
        float4 v = *(const float4*)(src + (size_t)c * NDIM + n0 + j4 * 4);
        Tt[j4 * 4 + 0][c] = v.x;
        Tt[j4 * 4 + 1][c] = v.y;
        Tt[j4 * 4 + 2][c] = v.z;
        Tt[j4 * 4 + 3][c] = v.w;
    }
    __syncthreads();
    {
        int j = tid & 63, part = tid >> 6;
        float ss = 0.f;
        #pragma unroll 8
        for (int c = part * 32; c < part * 32 + 32; ++c) { float x = Tt[j][c]; ss += x * x; }
        psum[part][j] = ss;
    }
    __syncthreads();
    if (tid < 64) {
        float s = psum[0][tid] + psum[1][tid] + psum[2][tid] + psum[3][tid];
        rn[tid] = 1.0f / fmaxf(sqrtf(s), 1e-12f);
    }
    __syncthreads();

    __hip_bfloat16* dstT = (__hip_bfloat16*)((char*)ws + (blockIdx.z == 0 ? KT_OFF : QT_OFF))
                           + ((size_t)b * NDIM + n0) * CDIM;
    #pragma unroll
    for (int i = 0; i < 8; ++i) {
        int f = tid + i * 256;
        int j = f >> 5, c4 = f & 31;
        float r = rn[j] * zscale;
        float4 v = *(const float4*)&Tt[j][c4 * 4];
        uint2 pk; pk.x = pack2bf(v.x * r, v.y * r); pk.y = pack2bf(v.z * r, v.w * r);
        *(uint2*)((unsigned short*)dstT + (size_t)j * CDIM + c4 * 4) = pk;
    }
    if (blockIdx.z == 0) {
        __hip_bfloat16* vb = (__hip_bfloat16*)((char*)ws + VB_OFF) + (size_t)b * CDIM * NDIM + n0;
        #pragma unroll
        for (int i = 0; i < 8; ++i) {
            int f = tid + i * 256;
            int c = f >> 4, j4 = f & 15;
            float x0 = Tt[j4 * 4 + 0][c], x1 = Tt[j4 * 4 + 1][c];
            float x2 = Tt[j4 * 4 + 2][c], x3 = Tt[j4 * 4 + 3][c];
            uint2 pv; pv.x = pack2bf(x0, x1); pv.y = pack2bf(x2, x3);
            *(uint2*)((unsigned short*)vb + (size_t)c * NDIM + j4 * 4) = pv;
        }
    } else if (blockIdx.x == 0 && b == 0) {
        // folded prep_w
        __hip_bfloat16* wT = (__hip_bfloat16*)((char*)ws + WT_OFF);
        float* sc = (float*)((char*)ws + SC_OFF);
        float* bi = (float*)((char*)ws + BI_OFF);
        #pragma unroll
        for (int i = 0; i < 64; ++i) {
            int f = tid + i * 256;
            int c = f >> 7, o = f & 127;
            wT[o * 128 + c] = __hip_bfloat16(wgt[c * 128 + o]);
        }
        if (tid < 128) {
            float inv = rsqrtf(var[tid] + 1e-5f);
            float s = inv * gamma[tid];
            sc[tid] = s;
            bi[tid] = beta[tid] - mean[tid] * s;
        }
    }
}

// ---------------------------------------------------------------------------
// Pass 2 (flash7): TWO independent 4-wave blocks per CU (barrier decoupling).
// Grid 512 (2 blocks/CU), batch = bx&7 (XCD-pinned), m-tile = 64, body 64-n.
// 256 thr = 4 waves: wave = (nt = w&1 -> 32-n slice, mt = w>>1 -> 32-m).
// S^T = K.Q^T (A=K from LDS, B=Q resident); P = 2^(S') in-register via
// permlane32_swap; O^T += V.P^T. ONE drain+barrier per 64-n body; the
// co-resident sibling block fills the stall.
// LDS 64KB/block: dbuf [K 16K][V 16K] @0/@32768 -> all ds offsets fit the
// 16-bit imm (zero addressing VALU). V rows are c-PAIRS of 256B
// (slot = ((c&1)<<3|chunk) ^ ((c>>1)&15)) -> 2-way bank = free.
// Epilogue overlays: oStg f32 32KB@0, lLds f32[4][32]@32768,
// sAgg bf16[64][128]swz@36864, sRes f32[128][72]@0.
// ---------------------------------------------------------------------------
__global__ __launch_bounds__(256, 2) void flash7(const void* __restrict__ ws_,
                                                 float* __restrict__ out) {
    extern __shared__ char smem[];
    const char* ws = (const char*)ws_;
    const __hip_bfloat16* Qt = (const __hip_bfloat16*)(ws + QT_OFF);
    const __hip_bfloat16* Kt = (const __hip_bfloat16*)(ws + KT_OFF);
    const __hip_bfloat16* Vb = (const __hip_bfloat16*)(ws + VB_OFF);
    const __hip_bfloat16* wT = (const __hip_bfloat16*)(ws + WT_OFF);
    const float* scale = (const float*)(ws + SC_OFF);
    const float* bias  = (const float*)(ws + BI_OFF);

    const int bx = blockIdx.x;
    const int b  = bx & 7;
    const int m0 = (bx >> 3) * 64;
    const int tid = threadIdx.x;
    const int w = tid >> 6, lane = tid & 63;
    const int hf = lane >> 5;          // lane half
    const int l31 = lane & 31;
    const int nt = w & 1;              // 32-n slice of the 64-n body
    const int mt = w >> 1;             // 32-m subtile (0..1)

    const char* kgb = (const char*)(Kt + (size_t)b * NDIM * CDIM);
    const char* vgb = (const char*)(Vb + (size_t)b * CDIM * NDIM);

    // resident Q B-frags: B[k=c][col=m], col = l31 -> m = m0 + mt*32 + l31
    bf16x8 qb[8];
    {
        const char* qrow = (const char*)Qt + ((size_t)b * NDIM + m0 + mt * 32 + l31) * 256 + hf * 16;
        #pragma unroll
        for (int s = 0; s < 8; ++s) qb[s] = *(const bf16x8*)(qrow + s * 32);
    }

    // LDS read offsets, absolute within buf0 (buf1 = +32768 instr offset)
    unsigned kOff[8];
    {
        int nn = nt * 32 + l31;
        #pragma unroll
        for (int s = 0; s < 8; ++s)
            kOff[s] = nn * 256 + (((2 * s + hf) ^ (nn & 15)) * 16);
    }
    unsigned vOff[2][4];
    #pragma unroll
    for (int t = 0; t < 2; ++t)
        #pragma unroll
        for (int ca = 0; ca < 4; ++ca) {
            int c = ca * 32 + l31;
            int rr = c >> 1;
            int sl = (((c & 1) << 3) | (nt * 4 + t * 2 + hf)) ^ (rr & 15);
            vOff[t][ca] = 16384 + rr * 256 + sl * 16;
        }

    // staging lane offsets (glds: wave-uniform LDS base + lane*16, swizzle on SOURCE)
    unsigned kLane[4], vLane[4];
    #pragma unroll
    for (int i = 0; i < 4; ++i) {
        int slot = i * 256 + tid;
        int r = slot >> 4, j = slot & 15;
        kLane[i] = r * 256 + ((j ^ (r & 15)) * 16);
        int u = j ^ (r & 15);
        int c = r * 2 + (u >> 3), ch = u & 7;
        vLane[i] = c * 8192 + ch * 16;
    }
    const unsigned kDstB = w * 1024;
    const unsigned vDstB = 16384 + w * 1024;

    f32x16 oacc[4];
    #pragma unroll
    for (int ca = 0; ca < 4; ++ca)
        #pragma unroll
        for (int i = 0; i < 16; ++i) oacc[ca][i] = 0.f;
    float lacc = 0.f;

    // prologue: stage tile 0 into buf0
    #pragma unroll
    for (int i = 0; i < 4; ++i) glds16(kgb + kLane[i], smem + kDstB + i * 4096);
    #pragma unroll
    for (int i = 0; i < 4; ++i) glds16(vgb + vLane[i], smem + vDstB + i * 4096);
    unsigned kOffG = 16384;            // byte offset of next K tile to stage
    unsigned vOffG = 128;              // byte offset of next V tile to stage

    // P = 2^(S'); pack rows into dwords; C-layout row = (reg&3)+8*(reg>>2)+4*hf.
    // permlane32_swap pairs (0,2),(1,3) lands the B-frag words in place.
    auto softmax_pf = [&](const f32x16& s, bf16x8* pf) {
        unsigned d[8];
        float lsum = 0.f;
        #pragma unroll
        for (int rq = 0; rq < 4; ++rq) {
            float e0 = vexp2(s[rq * 4 + 0]);
            float e1 = vexp2(s[rq * 4 + 1]);
            float e2 = vexp2(s[rq * 4 + 2]);
            float e3 = vexp2(s[rq * 4 + 3]);
            lsum += (e0 + e1) + (e2 + e3);
            d[rq * 2 + 0] = pack2bf(e0, e1);
            d[rq * 2 + 1] = pack2bf(e2, e3);
        }
        lacc += lsum;
        #pragma unroll
        for (int t = 0; t < 2; ++t) {
            pls32(d[4 * t + 0], d[4 * t + 2]);
            pls32(d[4 * t + 1], d[4 * t + 3]);
            u32x4 tv;
            tv.x = d[4 * t + 0]; tv.y = d[4 * t + 1];
            tv.z = d[4 * t + 2]; tv.w = d[4 * t + 3];
            pf[t] = __builtin_bit_cast(bf16x8, tv);
        }
    };

    auto body = [&](const unsigned bo, const bool do_pref) {
        // tile(bo) ready: its glds issued one body ago; everyone exited prev body
        asm volatile("s_waitcnt vmcnt(0) lgkmcnt(0)\ns_barrier" ::: "memory");
        // prefetch next tile into other buffer immediately (max latency cover)
        if (do_pref) {
            const unsigned obo = bo ^ 32768u;
            #pragma unroll
            for (int i = 0; i < 4; ++i) glds16(kgb + kOffG + kLane[i], smem + (obo + kDstB + i * 4096));
            #pragma unroll
            for (int i = 0; i < 4; ++i) glds16(vgb + vOffG + vLane[i], smem + (obo + vDstB + i * 4096));
            kOffG += 16384;
            vOffG += 128;
        }

        // S^T = K.Q^T : D[n_local][m], 32x32, k=128
        f32x16 st;
        #pragma unroll
        for (int i = 0; i < 16; ++i) st[i] = 0.f;
        __builtin_amdgcn_s_setprio(1);
        #pragma unroll
        for (int s = 0; s < 8; ++s) {
            bf16x8 kf = *(const bf16x8*)(smem + bo + kOff[s]);
            st = mfma32(kf, qb[s], st);
        }
        __builtin_amdgcn_s_setprio(0);

        bf16x8 pf[2];
        softmax_pf(st, pf);

        // O^T += V.P^T : wave covers 128c x 32m over its 32-n slice
        __builtin_amdgcn_s_setprio(1);
        #pragma unroll
        for (int t = 0; t < 2; ++t)
            #pragma unroll
            for (int ca = 0; ca < 4; ++ca) {
                bf16x8 vf = *(const bf16x8*)(smem + bo + vOff[t][ca]);
                oacc[ca] = mfma32(vf, pf[t], oacc[ca]);
            }
        __builtin_amdgcn_s_setprio(0);
    };

    for (int ii = 0; ii < 32; ++ii) {
        body(0u, true);
        body(32768u, ii != 31);
    }

    // ---- epilogue ----
    float lw = lacc + __shfl_xor(lacc, 32, 64);   // full 32-n of this wave's slice
    __syncthreads();                               // E0: tiles fully consumed
    float* lLds = (float*)(smem + 32768);          // [4][32]
    if (lane < 32) lLds[w * 32 + lane] = lw;
    if (w & 1) {                                   // odd (nt=1) waves stage O^T
        float4* dst = (float4*)smem + (w >> 1) * 1024 + lane;
        #pragma unroll
        for (int ca = 0; ca < 4; ++ca)
            #pragma unroll
            for (int rq = 0; rq < 4; ++rq) {
                float4 t = { oacc[ca][rq * 4 + 0], oacc[ca][rq * 4 + 1],
                             oacc[ca][rq * 4 + 2], oacc[ca][rq * 4 + 3] };
                dst[(ca * 4 + rq) * 64] = t;
            }
    }
    __syncthreads();                               // E1
    char* sAgg = smem + 36864;                     // bf16 [64 m][128 c] swizzled
    if (!(w & 1)) {                                // even waves combine + normalize
        float linv = 1.0f / (lLds[w * 32 + l31] + lLds[(w + 1) * 32 + l31]);
        const float4* srcp = (const float4*)smem + (w >> 1) * 1024 + lane;
        int m = (w >> 1) * 32 + l31;
        char* aggRow = sAgg + m * 256;
        const int mx = (m & 7) << 1;
        #pragma unroll
        for (int ca = 0; ca < 4; ++ca)
            #pragma unroll
            for (int rq = 0; rq < 4; ++rq) {
                float4 ov = srcp[(ca * 4 + rq) * 64];
                float v0 = (oacc[ca][rq * 4 + 0] + ov.x) * linv;
                float v1 = (oacc[ca][rq * 4 + 1] + ov.y) * linv;
                float v2 = (oacc[ca][rq * 4 + 2] + ov.z) * linv;
                float v3 = (oacc[ca][rq * 4 + 3] + ov.w) * linv;
                int cq = ca * 8 + rq * 2 + hf;     // c-quad of rows (reg-quad)
                uint2 pk; pk.x = pack2bf(v0, v1); pk.y = pack2bf(v2, v3);
                *(uint2*)(aggRow + ((cq ^ mx) * 8)) = pk;
            }
    }
    __syncthreads();                               // E2: sAgg ready

    // projection (16x16 MFMA): wave -> m-slice w*16, all 128 o
    const int li = lane & 15, q = lane >> 4;
    const int pm = w * 16 + li;
    f32x4 racc[8];
    #pragma unroll
    for (int ob = 0; ob < 8; ++ob) { racc[ob][0]=0.f; racc[ob][1]=0.f; racc[ob][2]=0.f; racc[ob][3]=0.f; }
    #pragma unroll
    for (int ks = 0; ks < 4; ++ks) {
        int slot8 = ((ks * 4 + q) * 2) ^ ((li & 7) << 1);
        bf16x8 af = *(const bf16x8*)(sAgg + pm * 256 + slot8 * 8);
        #pragma unroll
        for (int ob = 0; ob < 8; ++ob) {
            bf16x8 wf = *(const bf16x8*)((const char*)wT + (ob * 16 + li) * 256 + ks * 64 + q * 16);
            racc[ob] = mfma16(af, wf, racc[ob]);
        }
    }

    // LeakyReLU + BN(eval) -> transpose buffer
    float* sRes = (float*)smem;                    // [128 o][72 m]
    #pragma unroll
    for (int ob = 0; ob < 8; ++ob) {
        int oo = ob * 16 + li;
        float sc = scale[oo], bi = bias[oo];
        #pragma unroll
        for (int r = 0; r < 4; ++r) {
            float v = racc[ob][r];
            v = (v >= 0.0f) ? v : 0.01f * v;
            v = v * sc + bi;
            sRes[oo * 72 + w * 16 + q * 4 + r] = v;
        }
    }
    __syncthreads();                               // E3

    // coalesced store: out[b][o][m0..m0+63]
    float* outb = out + (size_t)b * CDIM * NDIM + m0;
    #pragma unroll
    for (int i = 0; i < 8; ++i) {
        int f = tid + i * 256;                     // 2048 float4s
        int o = f >> 4, mq = f & 15;
        *(float4*)(outb + (size_t)o * NDIM + mq * 4) = *(const float4*)(sRes + o * 72 + mq * 4);
    }
}

extern "C" void kernel_launch(void* const* d_in, const int* in_sizes, int n_in,
                              void* d_out, int out_size, void* d_ws, size_t ws_size,
                              hipStream_t stream) {
    const float* input  = (const float*)d_in[0];
    const float* tg     = (const float*)d_in[1];
    const float* weight = (const float*)d_in[2];
    const float* gamma  = (const float*)d_in[3];
    const float* beta   = (const float*)d_in[4];
    const float* rmean  = (const float*)d_in[5];
    const float* rvar   = (const float*)d_in[6];
    float* out = (float*)d_out;

    (void)in_sizes; (void)n_in; (void)out_size; (void)ws_size;

    hipFuncSetAttribute(reinterpret_cast<const void*>(flash7),
                        hipFuncAttributeMaxDynamicSharedMemorySize, 65536);

    dim3 gprep(NDIM / 64, BATCH, 2);
    prep_nt<<<gprep, 256, 0, stream>>>(input, tg, weight, gamma, beta, rmean, rvar, d_ws);
    flash7<<<dim3(512), 256, 65536, stream>>>(d_ws, out);
}